// Round 6
// baseline (250.873 us; speedup 1.0000x reference)
//
#include <hip/hip_runtime.h>
#include <math.h>

typedef unsigned short u16;
typedef unsigned int u32;
typedef __attribute__((ext_vector_type(8))) short bf16x8_t;
typedef __attribute__((ext_vector_type(4))) float f32x4_t;

#define S_LEN  2048
#define NH     16
#define DK     64
#define DMODEL 1024
#define MROWS  4096   // B*S

__device__ inline u16 f2b(float f) {
  union { float f; u32 u; } c; c.f = f;
  u32 u = c.u;
  return (u16)((u + 0x7fffu + ((u >> 16) & 1u)) >> 16);  // RNE bf16
}

// ---------------- cast fp32 -> bf16 ----------------
__global__ void cast_bf16_kernel(const float* __restrict__ src, u16* __restrict__ dst, int n) {
  int i = (blockIdx.x * blockDim.x + threadIdx.x) * 4;
  if (i + 3 < n) {
    float4 v = *(const float4*)(src + i);
    ushort4 o;
    o.x = f2b(v.x); o.y = f2b(v.y); o.z = f2b(v.z); o.w = f2b(v.w);
    *(ushort4*)(dst + i) = o;
  }
}

// ---------------- fused transpose+cast of the 4 weights: W [1024][1024] fp32 -> Wt [n][k] bf16 ----------------
__global__ void transpose_cast4_kernel(const float* __restrict__ W0, const float* __restrict__ W1,
                                       const float* __restrict__ W2, const float* __restrict__ W3,
                                       u16* __restrict__ D0, u16* __restrict__ D1,
                                       u16* __restrict__ D2, u16* __restrict__ D3) {
  const float* W; u16* Wt;
  switch (blockIdx.z) {
    case 0: W = W0; Wt = D0; break;
    case 1: W = W1; Wt = D1; break;
    case 2: W = W2; Wt = D2; break;
    default: W = W3; Wt = D3; break;
  }
  __shared__ float tile[32][33];
  int bc = blockIdx.x * 32, br = blockIdx.y * 32;
  int tx = threadIdx.x & 31, ty = threadIdx.x >> 5;  // 256 threads: ty 0..7
  #pragma unroll
  for (int yy = 0; yy < 32; yy += 8)
    tile[ty + yy][tx] = W[(size_t)(br + ty + yy) * DMODEL + bc + tx];
  __syncthreads();
  #pragma unroll
  for (int yy = 0; yy < 32; yy += 8)
    Wt[(size_t)(bc + ty + yy) * DMODEL + br + tx] = f2b(tile[tx][ty + yy]);
}

// ---------------- bias table: btab[h][delta+2047] = bias(h,delta) - 16  (softmax offset folded) ----------------
__global__ void bias_table_kernel(const float* __restrict__ rel_emb, float* __restrict__ btab) {
  int idx = blockIdx.x * 256 + threadIdx.x;
  if (idx >= NH * 4095) return;
  int h = idx / 4095;
  int dpos = idx - h * 4095;
  int delta = dpos - 2047;               // j - i; reference n = i - j
  int ret = (delta > 0) ? 16 : 0;        // (n < 0) * num_buckets(16)
  int n = delta < 0 ? -delta : delta;
  int bucket;
  if (n < 8) {
    bucket = ret + n;
  } else {
    float vf = logf((float)n * 0.125f) / 2.7725887222397811f * 8.0f;
    int vil = 8 + (int)vf;
    bucket = ret + (vil < 15 ? vil : 15);
  }
  btab[idx] = rel_emb[bucket * NH + h] - 16.0f;
}

// ---------------- global -> LDS DMA: wave-uniform LDS base, lane deposits 16B at base + lane*16 ----------------
__device__ __forceinline__ void stage16(const u16* gp_lane, u16* lds_base) {
#if __has_builtin(__builtin_amdgcn_global_load_lds)
  __builtin_amdgcn_global_load_lds((const __attribute__((address_space(1))) u32*)gp_lane,
                                   (__attribute__((address_space(3))) u32*)lds_base, 16, 0, 0);
#else
  *(uint4*)(lds_base + (threadIdx.x & 63) * 8) = *(const uint4*)gp_lane;
#endif
}

// ---------------- 128x128 bf16 MFMA GEMM, m97 DMA staging ----------------
// C[m][n] = sum_k A[m][k] * Bt[n][k].  A [4096][1024] bf16, Bt [N][1024] bf16.
// mode 0: C fp32 [4096][1024] (out projection)
// mode 1: fused QKV: Bt=[3072][1024]; n<1024 -> q16 [bh][s][64]; <2048 -> k16; else vt16 [bh][64][s]
__global__ __launch_bounds__(256) void gemm128_kernel(const u16* __restrict__ A,
                                                      const u16* __restrict__ Bt,
                                                      float* __restrict__ C,
                                                      u16* __restrict__ q16,
                                                      u16* __restrict__ k16,
                                                      u16* __restrict__ vt16,
                                                      int mode) {
  __shared__ __align__(16) u16 As[128 * 32];  // unpadded row-major [128][32] (DMA lane order)
  __shared__ __align__(16) u16 Bs[128 * 32];
  const int t = threadIdx.x, w = t >> 6, l = t & 63;
  const int c = l & 15, quad = l >> 4;
  const int m0 = blockIdx.x * 128, n0 = blockIdx.y * 128;
  const int wm = (w & 1) * 64, wn = (w >> 1) * 64;

  // DMA map: wave w stages rows w*32 .. w*32+31 (two 16-row slabs); lane l -> row l>>2, 16B chunk l&3
  const int sr = l >> 2;
  const int k8 = (l & 3) * 8;
  const u16* Ag0 = A  + (size_t)(m0 + w * 32 + sr) * DMODEL + k8;
  const u16* Ag1 = Ag0 + (size_t)16 * DMODEL;
  const u16* Bg0 = Bt + (size_t)(n0 + w * 32 + sr) * DMODEL + k8;
  const u16* Bg1 = Bg0 + (size_t)16 * DMODEL;
  u16* Al = As + w * 1024;   // w*32 rows * 32 cols
  u16* Bl = Bs + w * 1024;

  f32x4_t acc[16] = {};
  for (int k0 = 0; k0 < DMODEL; k0 += 32) {
    __syncthreads();   // prior frag reads done
    stage16(Ag0 + k0, Al);
    stage16(Ag1 + k0, Al + 512);
    stage16(Bg0 + k0, Bl);
    stage16(Bg1 + k0, Bl + 512);
    __syncthreads();   // compiler drains vmcnt before s_barrier
    bf16x8_t af[4], bfr[4];
    #pragma unroll
    for (int i = 0; i < 4; ++i) {
      af[i]  = *(const bf16x8_t*)(As + (wm + i * 16 + c) * 32 + quad * 8);
      bfr[i] = *(const bf16x8_t*)(Bs + (wn + i * 16 + c) * 32 + quad * 8);
    }
    #pragma unroll
    for (int mt = 0; mt < 4; ++mt)
      #pragma unroll
      for (int nt = 0; nt < 4; ++nt)
        acc[mt * 4 + nt] = __builtin_amdgcn_mfma_f32_16x16x32_bf16(af[mt], bfr[nt], acc[mt * 4 + nt], 0, 0, 0);
  }

  // C/D layout: col = lane&15, row = quad*4 + reg
  #pragma unroll
  for (int mt = 0; mt < 4; ++mt) {
    int grow0 = m0 + wm + mt * 16 + quad * 4;
    #pragma unroll
    for (int nt = 0; nt < 4; ++nt) {
      int gcol = n0 + wn + nt * 16 + c;
      f32x4_t v4 = acc[mt * 4 + nt];
      if (mode == 0) {
        #pragma unroll
        for (int r = 0; r < 4; ++r)
          C[(size_t)(grow0 + r) * DMODEL + gcol] = v4[r];
      } else {
        int which = gcol >> 10;
        int cc = gcol & 1023;
        int hh = cc >> 6, dk = cc & 63;
        int b = grow0 >> 11, s0 = grow0 & 2047;
        if (which == 2) {
          ushort4 o;
          o.x = f2b(v4[0]); o.y = f2b(v4[1]); o.z = f2b(v4[2]); o.w = f2b(v4[3]);
          *(ushort4*)(vt16 + (((size_t)(b * NH + hh)) * DK + dk) * S_LEN + s0) = o;
        } else {
          u16* dst = (which == 0 ? q16 : k16) + (((size_t)(b * NH + hh)) * S_LEN + s0) * DK + dk;
          #pragma unroll
          for (int r = 0; r < 4; ++r) dst[(size_t)r * DK] = f2b(v4[r]);
        }
      }
    }
  }
}

// ---------------- MFMA flash attention: double-buffered K/V, one barrier per K-tile ----------------
// q,k: bf16 [bh][s][64]; vt: bf16 [bh][64][s]; ctx out: bf16 [b][s][1024]
#define ASTR 72   // u16 row stride (144 B): 16B-aligned, 2-way-max bank aliasing (free per m136)
__global__ __launch_bounds__(256, 3) void attn_mfma_kernel(const u16* __restrict__ q,
                                                           const u16* __restrict__ k,
                                                           const u16* __restrict__ vt,
                                                           const float* __restrict__ btab,
                                                           u16* __restrict__ ctx) {
  __shared__ __align__(16) u16 Ks[2][64 * ASTR];
  __shared__ __align__(16) u16 Vts[2][64 * ASTR];
  __shared__ __align__(16) u16 Ps[4 * 16 * ASTR];
  __shared__ float band[2][128];   // bias-16 for the 127 deltas of (q-tile, k-tile)

  const int t = threadIdx.x;
  const int w = t >> 6, l = t & 63;
  const int c = l & 15, quad = l >> 4;
  const int bh = blockIdx.y;
  const int h = bh & (NH - 1), b = bh >> 4;
  const int q0 = blockIdx.x * 64;

  const u16* qb = q + (size_t)bh * S_LEN * DK;
  const u16* kb = k + (size_t)bh * S_LEN * DK;
  const u16* vb = vt + (size_t)bh * DK * S_LEN;
  // band[d] = btab[h][2047 + (kt - q0 - 63) + d],  d = (key_col) - (q_row) + 63 in [0,126]
  const float* btp = btab + h * 4095 + (2047 - 63 - q0);

  // Q A-fragments (rows q0 + w*16 + c), registers for whole kernel
  bf16x8_t qfrag[2];
  {
    const u16* qp = qb + (size_t)(q0 + w * 16 + c) * DK + quad * 8;
    qfrag[0] = *(const bf16x8_t*)(qp);
    qfrag[1] = *(const bf16x8_t*)(qp + 32);
  }

  float lp[4] = {0.f, 0.f, 0.f, 0.f};   // per-lane partial row sums (rows quad*4+r)
  f32x4_t O[4] = {};

  // staging map (FULL tile coverage): rows srow and srow+32; 256 thr x 2 x 8 u16 = full 64x64 tile
  const int srow = t >> 3;            // 0..31
  const int sc8 = (t & 7) * 8;        // 0..56
  const u16* kg0 = kb + (size_t)srow * DK + sc8;        // + kt*DK per tile
  const u16* kg1 = kg0 + (size_t)32 * DK;
  const u16* vg0 = vb + (size_t)srow * S_LEN + sc8;     // + kt per tile
  const u16* vg1 = vg0 + (size_t)32 * S_LEN;
  const int loff0 = srow * ASTR + sc8, loff1 = (srow + 32) * ASTR + sc8;
  u16* Pw = Ps + w * 16 * ASTR;
  const int bnd0 = c - (w * 16 + quad * 4) + 63;      // + nt*16 - r  ->  [0,126]

  // preload tile 0 into buffer 0
  {
    uint4 kr0 = *(const uint4*)kg0, kr1 = *(const uint4*)kg1;
    uint4 vr0 = *(const uint4*)vg0, vr1 = *(const uint4*)vg1;
    *(uint4*)(Ks[0] + loff0) = kr0; *(uint4*)(Ks[0] + loff1) = kr1;
    *(uint4*)(Vts[0] + loff0) = vr0; *(uint4*)(Vts[0] + loff1) = vr1;
    if (t < 127) band[0][t] = btp[t];
  }
  __syncthreads();

  int pb = 0;
  for (int kt = 0; kt < S_LEN; kt += 64, pb ^= 1) {
    const bool more = (kt + 64) < S_LEN;
    uint4 kr0, kr1, vr0, vr1; float br;
    if (more) {   // issue next tile's global loads; latency hidden by compute below
      kr0 = *(const uint4*)(kg0 + (size_t)(kt + 64) * DK);
      kr1 = *(const uint4*)(kg1 + (size_t)(kt + 64) * DK);
      vr0 = *(const uint4*)(vg0 + (kt + 64));
      vr1 = *(const uint4*)(vg1 + (kt + 64));
      br = (t < 127) ? btp[kt + 64 + t] : 0.f;
    }

    // ---- S = Q K^T ----
    const u16* Kc = Ks[pb];
    const u16* Vc = Vts[pb];
    f32x4_t s4[4] = {};
    #pragma unroll
    for (int kc = 0; kc < 2; ++kc) {
      #pragma unroll
      for (int nt = 0; nt < 4; ++nt) {
        bf16x8_t bfr = *(const bf16x8_t*)(Kc + (nt * 16 + c) * ASTR + kc * 32 + quad * 8);
        s4[nt] = __builtin_amdgcn_mfma_f32_16x16x32_bf16(qfrag[kc], bfr, s4[nt], 0, 0, 0);
      }
    }

    // ---- p = exp(s + bias - 16); accumulate l; P -> LDS (half-up bf16) ----
    #pragma unroll
    for (int nt = 0; nt < 4; ++nt) {
      #pragma unroll
      for (int r = 0; r < 4; ++r) {
        float p = __expf(s4[nt][r] + band[pb][bnd0 + nt * 16 - r]);
        lp[r] += p;
        union { float f; u32 u; } cv; cv.f = p;
        Pw[(quad * 4 + r) * ASTR + nt * 16 + c] = (u16)((cv.u + 0x8000u) >> 16);
      }
    }

    // ---- O += P V (wave-synchronous P round-trip) ----
    #pragma unroll
    for (int kc = 0; kc < 2; ++kc) {
      bf16x8_t afr = *(const bf16x8_t*)(Pw + c * ASTR + kc * 32 + quad * 8);
      #pragma unroll
      for (int nt = 0; nt < 4; ++nt) {
        bf16x8_t bfr = *(const bf16x8_t*)(Vc + (nt * 16 + c) * ASTR + kc * 32 + quad * 8);
        O[nt] = __builtin_amdgcn_mfma_f32_16x16x32_bf16(afr, bfr, O[nt], 0, 0, 0);
      }
    }

    // ---- store next tile into the other buffer (no wave reads it this iter) ----
    if (more) {
      u16* Kn = Ks[pb ^ 1];
      u16* Vn = Vts[pb ^ 1];
      *(uint4*)(Kn + loff0) = kr0; *(uint4*)(Kn + loff1) = kr1;
      *(uint4*)(Vn + loff0) = vr0; *(uint4*)(Vn + loff1) = vr1;
      if (t < 127) band[pb ^ 1][t] = br;
    }
    __syncthreads();   // next-buffer writes visible; current-buffer reads complete
  }

  // ---- single deferred l reduction + epilogue ----
  #pragma unroll
  for (int off = 1; off < 16; off <<= 1)
    #pragma unroll
    for (int r = 0; r < 4; ++r)
      lp[r] += __shfl_xor(lp[r], off, 64);
  #pragma unroll
  for (int r = 0; r < 4; ++r) {
    float inv = 1.0f / lp[r];
    int s = q0 + w * 16 + quad * 4 + r;
    u16* cp = ctx + ((size_t)(b * S_LEN + s)) * DMODEL + h * DK + c;
    #pragma unroll
    for (int nt = 0; nt < 4; ++nt)
      cp[nt * 16] = f2b(O[nt][r] * inv);
  }
}

extern "C" void kernel_launch(void* const* d_in, const int* in_sizes, int n_in,
                              void* d_out, int out_size, void* d_ws, size_t ws_size,
                              hipStream_t stream) {
  const float* x   = (const float*)d_in[0];
  const float* Wq  = (const float*)d_in[1];
  const float* Wk  = (const float*)d_in[2];
  const float* Wv  = (const float*)d_in[3];
  const float* Wo  = (const float*)d_in[4];
  const float* rel = (const float*)d_in[5];
  float* out = (float*)d_out;

  char* ws = (char*)d_ws;
  size_t off = 0;
  auto carve = [&](size_t bytes) -> char* {
    char* p = ws + off;
    off += (bytes + 255) & ~(size_t)255;
    return p;
  };
  u16*   xb   = (u16*)  carve((size_t)MROWS * DMODEL * 2);       // x bf16
  u16*   Wall = (u16*)  carve((size_t)3 * DMODEL * DMODEL * 2);  // [Wq^T;Wk^T;Wv^T] bf16 [3072][1024]
  u16*   Wto  = (u16*)  carve((size_t)DMODEL * DMODEL * 2);
  u16*   qb16 = (u16*)  carve((size_t)4194304 * 2);              // [bh][s][64] bf16
  u16*   kb16 = (u16*)  carve((size_t)4194304 * 2);
  u16*   vt16 = (u16*)  carve((size_t)4194304 * 2);              // [bh][64][s] bf16
  float* btab = (float*)carve((size_t)NH * 4095 * 4);
  u16*   ctxb = (u16*)  carve((size_t)4194304 * 2);              // [b][s][1024] bf16

  cast_bf16_kernel<<<4096, 256, 0, stream>>>(x, xb, 4194304);
  dim3 tgrid(32, 32, 4);
  transpose_cast4_kernel<<<tgrid, 256, 0, stream>>>(
      Wq, Wk, Wv, Wo,
      Wall, Wall + (size_t)DMODEL * DMODEL, Wall + (size_t)2 * DMODEL * DMODEL, Wto);
  bias_table_kernel<<<(NH * 4095 + 255) / 256, 256, 0, stream>>>(rel, btab);

  dim3 qkvgrid(32, 24);  // M/128, 3072/128
  gemm128_kernel<<<qkvgrid, 256, 0, stream>>>(xb, Wall, nullptr, qb16, kb16, vt16, 1);

  dim3 agrid(S_LEN / 64, 32);  // q-tiles, B*H
  attn_mfma_kernel<<<agrid, 256, 0, stream>>>(qb16, kb16, vt16, btab, ctxb);

  dim3 ogrid(32, 8);
  gemm128_kernel<<<ogrid, 256, 0, stream>>>(ctxb, Wto, out, nullptr, nullptr, nullptr, 0);
}